// Round 9
// baseline (563.006 us; speedup 1.0000x reference)
//
#include <hip/hip_runtime.h>
#include <hip/hip_bf16.h>
#include <cstdint>

// VanillaLSTMCell: B=8192, I=H=1024.
// z = [x|h] @ [Wx;Wh]^T + b  (M=8192, N=4096, K=2048), LSTM pointwise fused.
//
// ROUND 13: single persistent kernel = pack phase + device-scope grid
// barrier + R10's gemm (best measured: 134us, 48% MfmaUtil). B-direct
// (R11/R12) is abandoned: with barrier-locked waves, a per-wave B VMEM load
// puts L2 latency inside the MFMA dep chain every iter (191us, 31%).
// Fusion kills the second launch + inter-kernel drain and makes the
// pack cost visible in one dispatch's counters.
// Co-residency proof (grid barrier safety): grid=512 = 256CU x 2 blk/CU;
// launch_bounds(512,4) -> <=128 unified regs (R10 fit at 64+64); LDS 72KB
// -> floor(160/72)=2. Barrier: threadfence + t0 atomicAdd + AGENT-scope
// acquire spin (volatile spin would deadlock on non-coherent per-XCD L2).

typedef __bf16 bf16;
typedef __attribute__((ext_vector_type(8))) bf16 bf16x8;
typedef __attribute__((ext_vector_type(4))) float f32x4;

#define CN_OFF 8388608  // 8192*1024, c_next offset in d_out

__device__ __forceinline__ void gload16(const bf16* g, bf16* l) {
  __builtin_amdgcn_global_load_lds(
      (const __attribute__((address_space(1))) void*)g,
      (__attribute__((address_space(3))) void*)l, 16, 0, 0);
}

__device__ __forceinline__ bf16x8 cvt8(f32x4 v0, f32x4 v1) {
  bf16x8 o;
  o[0]=(bf16)v0[0]; o[1]=(bf16)v0[1]; o[2]=(bf16)v0[2]; o[3]=(bf16)v0[3];
  o[4]=(bf16)v1[0]; o[5]=(bf16)v1[1]; o[6]=(bf16)v1[2]; o[7]=(bf16)v1[3];
  return o;
}

__device__ __forceinline__ float sigf(float v) { return 1.f / (1.f + __expf(-v)); }
__device__ __forceinline__ float tanhfast(float v) {
  v = fminf(15.f, fmaxf(-15.f, v));
  float e = __expf(2.f * v);
  return (e - 1.f) / (e + 1.f);
}

// Layouts (unchanged):
// A2[mb(64)][kt(64)][wm(2)][mi(4)][lane(64)][8]:
//   m = mb*128 + wm*64 + mi*16 + (lane&15), k = kt*32 + (lane>>4)*8
// B2[nb(32)][kt(64)][wn(2)][gate(4)][lane(64)][8]:
//   j = (nb*2+wn)*16 + (lane&15), k = kt*32 + (lane>>4)*8
__global__ __launch_bounds__(512, 4) void lstm_fused(
    const float* __restrict__ x, const float* __restrict__ h,
    const float* __restrict__ wxi, const float* __restrict__ whi,
    const float* __restrict__ wxf, const float* __restrict__ whf,
    const float* __restrict__ wxo, const float* __restrict__ who,
    const float* __restrict__ wxg, const float* __restrict__ whg,
    const float* __restrict__ bxi, const float* __restrict__ bhi,
    const float* __restrict__ bxf, const float* __restrict__ bhf,
    const float* __restrict__ bxo, const float* __restrict__ bho,
    const float* __restrict__ bxg, const float* __restrict__ bhg,
    const float* __restrict__ c, float* __restrict__ out,
    bf16* __restrict__ A2, bf16* __restrict__ B2, float* __restrict__ Bcomb,
    unsigned int* __restrict__ cnt) {
  __shared__ __align__(16) bf16 lds[36864];   // 72KB = 3 gemm bufs x 12288
  const int t   = threadIdx.x;
  const int bid = blockIdx.x;                  // 512 blocks

  // ================= phase 1: pack (2 groups of 256 threads) =================
  {
    const int g  = t >> 8;            // 0/1
    const int ts = t & 255;
    bf16* ldsg = lds + g * 8192;      // 16KB per group

    // ---- A units: 2048 total, 4/block (2 per group) ----
#pragma unroll 1
    for (int it = 0; it < 2; ++it) {
      const int uA = bid * 4 + g * 2 + it;
      const int mb = uA >> 5;
      const int wm = (uA >> 4) & 1;
      const int q  = uA & 15;                  // col chunk [q*128, +128)
      const int rowbase = mb * 128 + wm * 64;
      const float* srcM; int k0;
      if (q < 8) { srcM = x; k0 = q * 128; } else { srcM = h; k0 = q * 128 - 1024; }
#pragma unroll
      for (int r = 0; r < 4; ++r) {
        const int rl = r * 16 + (ts >> 4);     // 0..63
        const int cc = (ts & 15) * 8;
        const float* s = srcM + (size_t)(rowbase + rl) * 1024 + k0 + cc;
        f32x4 v0 = *(const f32x4*)s;
        f32x4 v1 = *(const f32x4*)(s + 4);
        const int chunkS = (ts & 15) ^ (rl & 7);
        *(bf16x8*)((char*)ldsg + rl * 256 + chunkS * 16) = cvt8(v0, v1);
      }
      __syncthreads();
#pragma unroll
      for (int r = 0; r < 4; ++r) {
        const int idx = r * 256 + ts;          // 0..1023
        const int fj  = idx >> 6;              // ktL*4 + mi
        const int ktL = fj >> 2, mi = fj & 3;
        const int l   = idx & 63;
        const int srow = mi * 16 + (l & 15);
        const int chunkS = (ktL * 4 + (l >> 4)) ^ (srow & 7);
        bf16x8 o = *(const bf16x8*)((const char*)ldsg + srow * 256 + chunkS * 16);
        size_t el = ((size_t)mb * 64 + q * 4 + ktL) * 4096 + (size_t)wm * 2048 + mi * 512 + l * 8;
        *(bf16x8*)(A2 + el) = o;
      }
      __syncthreads();
    }

    // ---- B units: 2048 total, 4/block (2 per group) ----
#pragma unroll 1
    for (int it = 0; it < 2; ++it) {
      const int uB = bid * 4 + g * 2 + it;
      const int nb   = uB >> 6;
      const int gate = (uB >> 4) & 3;
      const int q    = uB & 15;
      const float* wxm = (gate == 0) ? wxi : (gate == 1) ? wxf : (gate == 2) ? wxo : wxg;
      const float* whm = (gate == 0) ? whi : (gate == 1) ? whf : (gate == 2) ? who : whg;
      const float* srcM; int k0;
      if (q < 8) { srcM = wxm; k0 = q * 128; } else { srcM = whm; k0 = q * 128 - 1024; }
      const int jbase = nb * 32;
#pragma unroll
      for (int r = 0; r < 2; ++r) {
        const int rl = r * 16 + (ts >> 4);     // 0..31
        const int cc = (ts & 15) * 8;
        const float* s = srcM + (size_t)(jbase + rl) * 1024 + k0 + cc;
        f32x4 v0 = *(const f32x4*)s;
        f32x4 v1 = *(const f32x4*)(s + 4);
        const int chunkS = (ts & 15) ^ (rl & 7);
        *(bf16x8*)((char*)ldsg + rl * 256 + chunkS * 16) = cvt8(v0, v1);
      }
      __syncthreads();
#pragma unroll
      for (int r = 0; r < 2; ++r) {
        const int idx = r * 256 + ts;          // 0..511
        const int fj  = idx >> 6;              // ktL*2 + wn
        const int ktL = fj >> 1, wn = fj & 1;
        const int l   = idx & 63;
        const int srow = wn * 16 + (l & 15);
        const int chunkS = (ktL * 4 + (l >> 4)) ^ (srow & 7);
        bf16x8 o = *(const bf16x8*)((const char*)ldsg + srow * 256 + chunkS * 16);
        size_t el = ((size_t)nb * 64 + q * 4 + ktL) * 4096 + (size_t)wn * 2048 + gate * 512 + l * 8;
        *(bf16x8*)(B2 + el) = o;
      }
      if (q == 0 && ts < 32) {
        const float* bxv = (gate == 0) ? bxi : (gate == 1) ? bxf : (gate == 2) ? bxo : bxg;
        const float* bhv = (gate == 0) ? bhi : (gate == 1) ? bhf : (gate == 2) ? bho : bhg;
        const int wn = ts >> 4, jl = ts & 15;
        const int j = nb * 32 + wn * 16 + jl;
        Bcomb[(nb * 2 + wn) * 64 + gate * 16 + jl] = bxv[j] + bhv[j];
      }
      __syncthreads();
    }
  }

  // ================= device-scope grid barrier (512 blocks) =================
  __syncthreads();
  __threadfence();                       // each thread releases its writes
  if (t == 0) {
    atomicAdd(cnt, 1u);                  // device-scope by default (m20)
    while (__hip_atomic_load(cnt, __ATOMIC_ACQUIRE, __HIP_MEMORY_SCOPE_AGENT) < 512u)
      __builtin_amdgcn_s_sleep(2);       // acquire load invalidates L1/L2
  }
  __syncthreads();

  // ================= phase 2: GEMM, two 256x128 tiles (R10 body) ============
  const int wave = t >> 6;
  const int lane = t & 63;
  const int xcd = bid & 7;
  const int idx = bid >> 3;              // 0..63
  const int nbP = xcd * 2 + (idx & 1);   // 0..15  (XCD owns nb [4x,4x+4))
  const int bm  = idx >> 1;              // 0..31

  const int wr  = wave >> 1;             // 0..3
  const int wn  = wave & 1;              // 0..1
  const int mbU = wr >> 1, wm2 = wr & 1;
  const int lrow = lane & 15, lkg = lane >> 4;

  const int tEl = t * 8;
  const int wEl = (t & ~63) * 8;

  const bf16* aSrc0 = A2 + (size_t)(2 * bm)     * 262144;
  const bf16* aSrc1 = A2 + (size_t)(2 * bm + 1) * 262144;
  const int aOff = mbU * 4096 + wm2 * 2048 + lane * 8;
  const int bOff = 8192 + wn * 2048 + lane * 8;

#pragma unroll 1
  for (int tl = 0; tl < 2; ++tl) {
    const int nb = nbP * 2 + tl;
    const bf16* bSrc = B2 + (size_t)nb * 262144;

    // buf layout (12288 elems): [A-mbU0: 4096][A-mbU1: 4096][B: 4096]
    auto stage = [&](int tile, int buf) {
      const size_t kOff = (size_t)tile * 4096;
      bf16* d = lds + buf * 12288;
      gload16(aSrc0 + kOff + tEl, d +        wEl);
      gload16(aSrc1 + kOff + tEl, d + 4096 + wEl);
      gload16(bSrc  + kOff + tEl, d + 8192 + wEl);
    };

    f32x4 acc[4][4] = {};   // acc[mi][gate]

    __syncthreads();        // prior tile's LDS reads all consumed
    stage(0, 0);
    stage(1, 1);            // 6 loads outstanding

    auto body = [&](int kt, int p, int pn, bool doStage, bool last) {
      if (last) asm volatile("s_waitcnt vmcnt(0)" ::: "memory");
      else      asm volatile("s_waitcnt vmcnt(3)" ::: "memory");
      __builtin_amdgcn_s_barrier();    // all waves' tile-kt loads landed
      asm volatile("" ::: "memory");
      if (doStage) stage(kt + 2, pn);  // overwrites buf of kt-1 (consumed)
      const bf16* bufA = lds + p * 12288 + aOff;
      const bf16* bufB = lds + p * 12288 + bOff;
      bf16x8 af[4], bfr[4];
#pragma unroll
      for (int i = 0; i < 4; ++i)
        af[i] = *(const bf16x8*)(bufA + i * 512);
#pragma unroll
      for (int g = 0; g < 4; ++g)
        bfr[g] = *(const bf16x8*)(bufB + g * 512);
      __builtin_amdgcn_s_setprio(1);
#pragma unroll
      for (int mi = 0; mi < 4; ++mi)
#pragma unroll
        for (int g = 0; g < 4; ++g)
          acc[mi][g] = __builtin_amdgcn_mfma_f32_16x16x32_bf16(af[mi], bfr[g], acc[mi][g], 0, 0, 0);
      __builtin_amdgcn_s_setprio(0);
    };

#pragma unroll 1
    for (int base = 0; base < 63; base += 3) {
      body(base,     0, 2, base     < 62, false);
      body(base + 1, 1, 0, base + 1 < 62, false);
      body(base + 2, 2, 1, base + 2 < 62, false);
    }
    body(63, 0, 0, false, true);

    // ---- register-resident LSTM epilogue for this tile ----
    const int jg = (nb * 2 + wn) * 16 + lrow;
    const int bbase = (nb * 2 + wn) * 64 + lrow;
    const float bi  = Bcomb[bbase +  0];
    const float bf_ = Bcomb[bbase + 16];
    const float bo  = Bcomb[bbase + 32];
    const float bg  = Bcomb[bbase + 48];

#pragma unroll
    for (int mi = 0; mi < 4; ++mi) {
      const int row0 = bm * 256 + mbU * 128 + wm2 * 64 + mi * 16 + lkg * 4;
      float cv[4];
#pragma unroll
      for (int r = 0; r < 4; ++r)
        cv[r] = c[(size_t)(row0 + r) * 1024 + jg];
#pragma unroll
      for (int r = 0; r < 4; ++r) {
        float zi = acc[mi][0][r] + bi;
        float zf = acc[mi][1][r] + bf_;
        float zo = acc[mi][2][r] + bo;
        float zg = acc[mi][3][r] + bg;
        float it = sigf(zi), ft = sigf(zf), ot = sigf(zo), gt = tanhfast(zg);
        float cn = ft * cv[r] + it * gt;
        size_t off = (size_t)(row0 + r) * 1024 + jg;
        out[off] = ot * tanhfast(cn);        // h_next
        out[CN_OFF + off] = cn;              // c_next
      }
    }
  }
}

extern "C" void kernel_launch(void* const* d_in, const int* in_sizes, int n_in,
                              void* d_out, int out_size, void* d_ws, size_t ws_size,
                              hipStream_t stream) {
  const float* x   = (const float*)d_in[0];
  const float* h   = (const float*)d_in[1];
  const float* c   = (const float*)d_in[2];
  const float* Wxi = (const float*)d_in[3];  const float* bxi = (const float*)d_in[4];
  const float* Whi = (const float*)d_in[5];  const float* bhi = (const float*)d_in[6];
  const float* Wxf = (const float*)d_in[7];  const float* bxf = (const float*)d_in[8];
  const float* Whf = (const float*)d_in[9];  const float* bhf = (const float*)d_in[10];
  const float* Wxo = (const float*)d_in[11]; const float* bxo = (const float*)d_in[12];
  const float* Who = (const float*)d_in[13]; const float* bho = (const float*)d_in[14];
  const float* Wxg = (const float*)d_in[15]; const float* bxg = (const float*)d_in[16];
  const float* Whg = (const float*)d_in[17]; const float* bhg = (const float*)d_in[18];
  float* out = (float*)d_out;

  bf16*  Abuf  = (bf16*)d_ws;                          // 32 MB
  bf16*  Wbuf  = Abuf + (size_t)8192 * 2048;           // 16 MB
  float* Bcomb = (float*)(Wbuf + (size_t)4096 * 2048); // 16 KB
  unsigned int* cnt = (unsigned int*)(Bcomb + 4096);   // 4 B, zeroed per call

  hipMemsetAsync(cnt, 0, sizeof(unsigned int), stream);
  lstm_fused<<<512, 512, 0, stream>>>(x, h,
                                      Wxi, Whi, Wxf, Whf, Wxo, Who, Wxg, Whg,
                                      bxi, bhi, bxf, bhf, bxo, bho, bxg, bhg,
                                      c, out, Abuf, Wbuf, Bcomb, cnt);
}